// Round 1
// baseline (1662.109 us; speedup 1.0000x reference)
//
#include <hip/hip_runtime.h>

#define L_SEQ 2048
#define DMODEL 1024
#define DINNER 2048

typedef __attribute__((ext_vector_type(8))) short bf16x8;
typedef __attribute__((ext_vector_type(4))) float f32x4;

__device__ __forceinline__ float bf2f(unsigned short u) {
  return __uint_as_float(((unsigned)u) << 16);
}
__device__ __forceinline__ unsigned short f2bf(float f) {
  unsigned u = __float_as_uint(f);
  return (unsigned short)((u + 0x7FFFu + ((u >> 16) & 1u)) >> 16);
}
__device__ __forceinline__ void gload_lds16(const void* g, void* l) {
  __builtin_amdgcn_global_load_lds(
      (const __attribute__((address_space(1))) void*)g,
      (__attribute__((address_space(3))) void*)l, 16, 0, 0);
}

// ---------------- fp32 -> bf16 convert (vectorized) ----------------
__global__ void cvt_f32_bf16(const float4* __restrict__ in, ushort4* __restrict__ out, int n4) {
  int i = blockIdx.x * blockDim.x + threadIdx.x;
  if (i >= n4) return;
  float4 v = in[i];
  ushort4 o;
  o.x = f2bf(v.x); o.y = f2bf(v.y); o.z = f2bf(v.z); o.w = f2bf(v.w);
  out[i] = o;
}

// ---------------- bf16 GEMM, C = A[M,K] * B[N,K]^T, m97 structure ----------------
// EPI: 0 = store bf16, 1 = softplus(v + aux[col]) -> f32, 2 = v + aux[row*N+col] -> f32
template <int EPI>
__global__ __launch_bounds__(256) void gemm_bt(
    const unsigned short* __restrict__ A, const unsigned short* __restrict__ B,
    int M, int N, int K,
    float* __restrict__ outf, unsigned short* __restrict__ outb,
    const float* __restrict__ aux) {
  __shared__ __align__(16) unsigned short As[128 * 32];
  __shared__ __align__(16) unsigned short Bs[128 * 32];
  const int tid = threadIdx.x;
  const int lane = tid & 63;
  const int wave = tid >> 6;
  const int wm = wave >> 1, wn = wave & 1;
  const int bm = blockIdx.y * 128, bn = blockIdx.x * 128;
  const int srow = tid >> 2, sc4 = tid & 3;

  const unsigned short* Ag = A + (size_t)(bm + srow) * K + sc4 * 8;
  const unsigned short* Bg = B + (size_t)(bn + srow) * K + sc4 * 8;
  unsigned short* AsW = &As[srow * 32 + sc4 * 8];  // byte offset == tid*16 (linear)
  unsigned short* BsW = &Bs[srow * 32 + sc4 * 8];

  f32x4 acc[4][4] = {};

  for (int k0 = 0; k0 < K; k0 += 32) {
    __syncthreads();
    gload_lds16(Ag + k0, AsW);
    gload_lds16(Ag + (size_t)64 * K + k0, AsW + 64 * 32);
    gload_lds16(Bg + k0, BsW);
    gload_lds16(Bg + (size_t)64 * K + k0, BsW + 64 * 32);
    __syncthreads();

    const int kz = (lane >> 4) * 8;
    const int r16 = lane & 15;
    bf16x8 a[4], b[4];
#pragma unroll
    for (int i = 0; i < 4; ++i)
      a[i] = *(const bf16x8*)&As[(wm * 64 + i * 16 + r16) * 32 + kz];
#pragma unroll
    for (int j = 0; j < 4; ++j)
      b[j] = *(const bf16x8*)&Bs[(wn * 64 + j * 16 + r16) * 32 + kz];
#pragma unroll
    for (int i = 0; i < 4; ++i)
#pragma unroll
      for (int j = 0; j < 4; ++j)
        acc[i][j] = __builtin_amdgcn_mfma_f32_16x16x32_bf16(a[i], b[j], acc[i][j], 0, 0, 0);
  }

  const int r16 = lane & 15;
  const int rq = lane >> 4;
#pragma unroll
  for (int i = 0; i < 4; ++i)
#pragma unroll
    for (int j = 0; j < 4; ++j)
#pragma unroll
      for (int r = 0; r < 4; ++r) {
        int row = bm + wm * 64 + i * 16 + rq * 4 + r;
        int col = bn + wn * 64 + j * 16 + r16;
        float v = acc[i][j][r];
        size_t off = (size_t)row * N + col;
        if (EPI == 0) {
          outb[off] = f2bf(v);
        } else if (EPI == 1) {
          float t = v + aux[col];
          outf[off] = (t > 15.f) ? t : log1pf(__expf(t));
        } else {
          outf[off] = v + aux[off];
        }
      }
}

// ---------------- causal depthwise conv (D_CONV=4) + SiLU; also silu(z) ----------------
__global__ void conv_silu(const unsigned short* __restrict__ xz,
                          const float* __restrict__ cw, const float* __restrict__ cb,
                          unsigned short* __restrict__ x_ssm,
                          unsigned short* __restrict__ sz_out) {
  int idx = blockIdx.x * 256 + threadIdx.x;  // over 2048*2048
  int l = idx >> 11, c = idx & 2047;
  float acc = cb[c];
  const float* w = cw + c * 4;
#pragma unroll
  for (int k = 0; k < 4; ++k) {
    int lt = l - 3 + k;
    if (lt >= 0) acc += bf2f(xz[(size_t)lt * 4096 + c]) * w[k];
  }
  x_ssm[idx] = f2bf(acc / (1.f + __expf(-acc)));
  float zv = bf2f(xz[(size_t)l * 4096 + 2048 + c]);
  sz_out[idx] = f2bf(zv / (1.f + __expf(-zv)));
}

// ---------------- W_x transpose: [32,2048] -> [2048,32] ----------------
__global__ void wx_transpose(const float* __restrict__ W_x, float* __restrict__ W_xT) {
  int idx = blockIdx.x * 256 + threadIdx.x;  // 65536
  int s = idx >> 11, e = idx & 2047;
  W_xT[e * 32 + s] = W_x[idx];
}

// ---------------- x_dbl = x_ssm @ W_x^T : [2048, 32] (one wave per row) ----------------
__global__ __launch_bounds__(256) void xdbl_kernel(
    const unsigned short* __restrict__ x_ssm, const float* __restrict__ W_xT,
    float* __restrict__ x_dbl) {
  int wv = blockIdx.x * 4 + (threadIdx.x >> 6);
  int lane = threadIdx.x & 63;
  int s = lane & 31, half = lane >> 5;
  const unsigned short* xr = x_ssm + (size_t)wv * 2048 + half * 1024;
  const float* wt = W_xT + (size_t)half * 1024 * 32 + s;
  float acc = 0.f;
#pragma unroll 8
  for (int e = 0; e < 1024; ++e) acc += bf2f(xr[e]) * wt[(size_t)e * 32];
  acc += __shfl_xor(acc, 32);
  if (half == 0) x_dbl[wv * 32 + s] = acc;
}

// ---------------- selective scan: h = exp(dt*A)*h + B*dt*x; y = h.C ----------------
__global__ __launch_bounds__(256) void scan_kernel(
    const float* __restrict__ dt, const unsigned short* __restrict__ x_ssm,
    const float* __restrict__ x_dbl, const float* __restrict__ A_log,
    const float* __restrict__ D_param, const unsigned short* __restrict__ silu_z,
    unsigned short* __restrict__ y_out) {
  int tid = threadIdx.x;
  int s = tid & 15, dch = tid >> 4;     // 16 states x 16 channels per block
  int d = blockIdx.x * 16 + dch;
  float Aval = -expf(A_log[d * 16 + s]);
  float Dp = D_param[d];
  float h = 0.f;
#pragma unroll 4
  for (int t = 0; t < 2048; ++t) {
    float dtv = dt[(size_t)t * 2048 + d];
    float xv = bf2f(x_ssm[(size_t)t * 2048 + d]);
    float Bv = x_dbl[t * 32 + s];
    float Cv = x_dbl[t * 32 + 16 + s];
    float dA = __expf(dtv * Aval);
    h = dA * h + Bv * dtv * xv;
    float yc = h * Cv;
    yc += __shfl_xor(yc, 1);
    yc += __shfl_xor(yc, 2);
    yc += __shfl_xor(yc, 4);
    yc += __shfl_xor(yc, 8);
    if (s == 0) {
      float y = yc + Dp * xv;
      float szv = bf2f(silu_z[(size_t)t * 2048 + d]);
      y_out[(size_t)t * 2048 + d] = f2bf(y * szv);
    }
  }
}

extern "C" void kernel_launch(void* const* d_in, const int* in_sizes, int n_in,
                              void* d_out, int out_size, void* d_ws, size_t ws_size,
                              hipStream_t stream) {
  const float* x      = (const float*)d_in[0];
  const float* W_in   = (const float*)d_in[1];
  const float* conv_w = (const float*)d_in[2];
  const float* conv_b = (const float*)d_in[3];
  const float* A_log  = (const float*)d_in[4];
  const float* D_par  = (const float*)d_in[5];
  const float* W_x    = (const float*)d_in[6];
  // d_in[7] = W_dt, d_in[8] = b_dt, d_in[9] = W_out
  const float* W_dt   = (const float*)d_in[7];
  const float* b_dt   = (const float*)d_in[8];
  const float* W_out  = (const float*)d_in[9];
  float* out = (float*)d_out;

  char* ws = (char*)d_ws;
  unsigned short* xbf    = (unsigned short*)(ws + 0);                       // 4MB
  unsigned short* Winbf  = (unsigned short*)(ws + ((size_t)4 << 20));       // 8MB
  unsigned short* Wdtbf  = (unsigned short*)(ws + ((size_t)12 << 20));      // 8MB
  unsigned short* Woutbf = (unsigned short*)(ws + ((size_t)20 << 20));      // 4MB
  unsigned short* xz     = (unsigned short*)(ws + ((size_t)24 << 20));      // 16MB
  unsigned short* xssm   = (unsigned short*)(ws + ((size_t)40 << 20));      // 8MB
  unsigned short* siluz  = (unsigned short*)(ws + ((size_t)48 << 20));      // 8MB
  float* dtf             = (float*)(ws + ((size_t)56 << 20));               // 16MB
  float* xdbl            = (float*)(ws + ((size_t)72 << 20));               // 256KB
  float* WxT             = (float*)(ws + ((size_t)72 << 20) + (256 << 10)); // 256KB
  unsigned short* yfin   = (unsigned short*)(ws + ((size_t)73 << 20));      // 8MB

  // fp32 -> bf16 converts
  cvt_f32_bf16<<<2048, 256, 0, stream>>>((const float4*)x, (ushort4*)xbf, (L_SEQ * DMODEL) / 4);
  cvt_f32_bf16<<<4096, 256, 0, stream>>>((const float4*)W_in, (ushort4*)Winbf, (2 * DINNER * DMODEL) / 4);
  cvt_f32_bf16<<<4096, 256, 0, stream>>>((const float4*)W_dt, (ushort4*)Wdtbf, (DINNER * DINNER) / 4);
  cvt_f32_bf16<<<2048, 256, 0, stream>>>((const float4*)W_out, (ushort4*)Woutbf, (DMODEL * DINNER) / 4);

  // GEMM1: xz[2048,4096] = x @ W_in^T  (bf16 out)
  gemm_bt<0><<<dim3(4096 / 128, L_SEQ / 128), 256, 0, stream>>>(
      xbf, Winbf, L_SEQ, 4096, DMODEL, nullptr, xz, nullptr);

  // conv + silu -> x_ssm; silu(z)
  conv_silu<<<(L_SEQ * DINNER) / 256, 256, 0, stream>>>(xz, conv_w, conv_b, xssm, siluz);

  // GEMM2: dt[2048,2048] = softplus(x_ssm @ W_dt^T + b_dt) (f32 out)
  gemm_bt<1><<<dim3(DINNER / 128, L_SEQ / 128), 256, 0, stream>>>(
      xssm, Wdtbf, L_SEQ, DINNER, DINNER, dtf, nullptr, b_dt);

  // x_dbl = x_ssm @ W_x^T  [2048,32]
  wx_transpose<<<(32 * DINNER) / 256, 256, 0, stream>>>(W_x, WxT);
  xdbl_kernel<<<L_SEQ / 4, 256, 0, stream>>>(xssm, WxT, xdbl);

  // selective scan -> y_final (gated) bf16
  scan_kernel<<<DINNER / 16, 256, 0, stream>>>(dtf, xssm, xdbl, A_log, D_par, siluz, yfin);

  // GEMM4: out[2048,1024] = y_final @ W_out^T + x (f32 out)
  gemm_bt<2><<<dim3(DMODEL / 128, L_SEQ / 128), 256, 0, stream>>>(
      yfin, Woutbf, L_SEQ, DMODEL, DINNER, out, nullptr, x);
}

// Round 2
// 445.917 us; speedup vs baseline: 3.7274x; 3.7274x over previous
//
#include <hip/hip_runtime.h>

#define L_SEQ 2048
#define DMODEL 1024
#define DINNER 2048
#define NCHUNK 64
#define TCHUNK 32

typedef __attribute__((ext_vector_type(8))) short bf16x8;
typedef __attribute__((ext_vector_type(4))) float f32x4;

__device__ __forceinline__ float bf2f(unsigned short u) {
  return __uint_as_float(((unsigned)u) << 16);
}
__device__ __forceinline__ unsigned short f2bf(float f) {
  unsigned u = __float_as_uint(f);
  return (unsigned short)((u + 0x7FFFu + ((u >> 16) & 1u)) >> 16);
}
__device__ __forceinline__ void gload_lds16(const void* g, void* l) {
  __builtin_amdgcn_global_load_lds(
      (const __attribute__((address_space(1))) void*)g,
      (__attribute__((address_space(3))) void*)l, 16, 0, 0);
}

// ---------------- fp32 -> bf16 convert (vectorized) ----------------
__global__ void cvt_f32_bf16(const float4* __restrict__ in, ushort4* __restrict__ out, int n4) {
  int i = blockIdx.x * blockDim.x + threadIdx.x;
  if (i >= n4) return;
  float4 v = in[i];
  ushort4 o;
  o.x = f2bf(v.x); o.y = f2bf(v.y); o.z = f2bf(v.z); o.w = f2bf(v.w);
  out[i] = o;
}

// ---------------- bf16 GEMM, C = A[M,K] * B[N,K]^T, m97 structure ----------------
// EPI: 0 = store bf16, 1 = softplus(v + aux[col]) -> f32, 2 = v + aux[row*N+col] -> f32
template <int EPI>
__global__ __launch_bounds__(256) void gemm_bt(
    const unsigned short* __restrict__ A, const unsigned short* __restrict__ B,
    int M, int N, int K,
    float* __restrict__ outf, unsigned short* __restrict__ outb,
    const float* __restrict__ aux) {
  __shared__ __align__(16) unsigned short As[128 * 32];
  __shared__ __align__(16) unsigned short Bs[128 * 32];
  const int tid = threadIdx.x;
  const int lane = tid & 63;
  const int wave = tid >> 6;
  const int wm = wave >> 1, wn = wave & 1;
  const int bm = blockIdx.y * 128, bn = blockIdx.x * 128;
  const int srow = tid >> 2, sc4 = tid & 3;

  const unsigned short* Ag = A + (size_t)(bm + srow) * K + sc4 * 8;
  const unsigned short* Bg = B + (size_t)(bn + srow) * K + sc4 * 8;
  unsigned short* AsW = &As[srow * 32 + sc4 * 8];
  unsigned short* BsW = &Bs[srow * 32 + sc4 * 8];

  f32x4 acc[4][4] = {};

  for (int k0 = 0; k0 < K; k0 += 32) {
    __syncthreads();
    gload_lds16(Ag + k0, AsW);
    gload_lds16(Ag + (size_t)64 * K + k0, AsW + 64 * 32);
    gload_lds16(Bg + k0, BsW);
    gload_lds16(Bg + (size_t)64 * K + k0, BsW + 64 * 32);
    __syncthreads();

    const int kz = (lane >> 4) * 8;
    const int r16 = lane & 15;
    bf16x8 a[4], b[4];
#pragma unroll
    for (int i = 0; i < 4; ++i)
      a[i] = *(const bf16x8*)&As[(wm * 64 + i * 16 + r16) * 32 + kz];
#pragma unroll
    for (int j = 0; j < 4; ++j)
      b[j] = *(const bf16x8*)&Bs[(wn * 64 + j * 16 + r16) * 32 + kz];
#pragma unroll
    for (int i = 0; i < 4; ++i)
#pragma unroll
      for (int j = 0; j < 4; ++j)
        acc[i][j] = __builtin_amdgcn_mfma_f32_16x16x32_bf16(a[i], b[j], acc[i][j], 0, 0, 0);
  }

  const int r16 = lane & 15;
  const int rq = lane >> 4;
#pragma unroll
  for (int i = 0; i < 4; ++i)
#pragma unroll
    for (int j = 0; j < 4; ++j)
#pragma unroll
      for (int r = 0; r < 4; ++r) {
        int row = bm + wm * 64 + i * 16 + rq * 4 + r;
        int col = bn + wn * 64 + j * 16 + r16;
        float v = acc[i][j][r];
        size_t off = (size_t)row * N + col;
        if (EPI == 0) {
          outb[off] = f2bf(v);
        } else if (EPI == 1) {
          float t = v + aux[col];
          outf[off] = (t > 15.f) ? t : log1pf(__expf(t));
        } else {
          outf[off] = v + aux[off];
        }
      }
}

// ---------------- causal depthwise conv (D_CONV=4) + SiLU; also silu(z) ----------------
__global__ void conv_silu(const unsigned short* __restrict__ xz,
                          const float* __restrict__ cw, const float* __restrict__ cb,
                          unsigned short* __restrict__ x_ssm,
                          unsigned short* __restrict__ sz_out) {
  int idx = blockIdx.x * 256 + threadIdx.x;  // over 2048*2048
  int l = idx >> 11, c = idx & 2047;
  float acc = cb[c];
  const float* w = cw + c * 4;
#pragma unroll
  for (int k = 0; k < 4; ++k) {
    int lt = l - 3 + k;
    if (lt >= 0) acc += bf2f(xz[(size_t)lt * 4096 + c]) * w[k];
  }
  x_ssm[idx] = f2bf(acc / (1.f + __expf(-acc)));
  float zv = bf2f(xz[(size_t)l * 4096 + 2048 + c]);
  sz_out[idx] = f2bf(zv / (1.f + __expf(-zv)));
}

// ---------------- W_x transpose: [32,2048] -> [2048,32] ----------------
__global__ void wx_transpose(const float* __restrict__ W_x, float* __restrict__ W_xT) {
  int idx = blockIdx.x * 256 + threadIdx.x;  // 65536
  int s = idx >> 11, e = idx & 2047;
  W_xT[e * 32 + s] = W_x[idx];
}

// ---------------- x_dbl = x_ssm @ W_x^T : [2048, 32] (one wave per row) ----------------
__global__ __launch_bounds__(256) void xdbl_kernel(
    const unsigned short* __restrict__ x_ssm, const float* __restrict__ W_xT,
    float* __restrict__ x_dbl) {
  int wv = blockIdx.x * 4 + (threadIdx.x >> 6);
  int lane = threadIdx.x & 63;
  int s = lane & 31, half = lane >> 5;
  const unsigned short* xr = x_ssm + (size_t)wv * 2048 + half * 1024;
  const float* wt = W_xT + (size_t)half * 1024 * 32 + s;
  float acc = 0.f;
#pragma unroll 8
  for (int e = 0; e < 1024; ++e) acc += bf2f(xr[e]) * wt[(size_t)e * 32];
  acc += __shfl_xor(acc, 32);
  if (half == 0) x_dbl[wv * 32 + s] = acc;
}

// ---------------- chunked parallel scan ----------------
// Pass A: per-chunk local scan from h=0; emit P = prod(dA), Hloc = local end state.
__global__ __launch_bounds__(256) void scan_passA(
    const float* __restrict__ dt, const unsigned short* __restrict__ x_ssm,
    const float* __restrict__ x_dbl, const float* __restrict__ A_log,
    float* __restrict__ Pout, float* __restrict__ Hout) {
  int tid = threadIdx.x;
  int s = tid & 15, dch = tid >> 4;       // 16 channels x 16 states per block
  int blk = blockIdx.x;                    // 8192 = 128 d-blocks x 64 chunks
  int c = blk & (NCHUNK - 1), db = blk >> 6;
  int d = db * 16 + dch;
  int t0 = c * TCHUNK;
  float Aval = -expf(A_log[d * 16 + s]);
  float h = 0.f, P = 1.f;
#pragma unroll 8
  for (int i = 0; i < TCHUNK; ++i) {
    int t = t0 + i;
    float dtv = dt[(size_t)t * 2048 + d];
    float xv = bf2f(x_ssm[(size_t)t * 2048 + d]);
    float Bv = x_dbl[t * 32 + s];
    float dA = __expf(dtv * Aval);
    h = dA * h + Bv * dtv * xv;
    P *= dA;
  }
  size_t o = (size_t)c * 32768 + d * 16 + s;
  Pout[o] = P;
  Hout[o] = h;
}

// Pass B: serial combine over chunks; emit chunk-entry states.
__global__ __launch_bounds__(256) void scan_passB(
    const float* __restrict__ P, const float* __restrict__ Hloc,
    float* __restrict__ Hinit) {
  int i = blockIdx.x * 256 + threadIdx.x;  // 32768 (d,s) pairs
  float h = 0.f;
#pragma unroll 8
  for (int c = 0; c < NCHUNK; ++c) {
    size_t o = (size_t)c * 32768 + i;
    float p = P[o];
    float hl = Hloc[o];
    Hinit[o] = h;
    h = hl + p * h;
  }
}

// Pass C: re-run each chunk from its entry state; emit gated y (bf16).
__global__ __launch_bounds__(256) void scan_passC(
    const float* __restrict__ dt, const unsigned short* __restrict__ x_ssm,
    const float* __restrict__ x_dbl, const float* __restrict__ A_log,
    const float* __restrict__ D_param, const unsigned short* __restrict__ silu_z,
    const float* __restrict__ Hinit, unsigned short* __restrict__ y_out) {
  int tid = threadIdx.x;
  int s = tid & 15, dch = tid >> 4;
  int blk = blockIdx.x;
  int c = blk & (NCHUNK - 1), db = blk >> 6;
  int d = db * 16 + dch;
  int t0 = c * TCHUNK;
  float Aval = -expf(A_log[d * 16 + s]);
  float Dp = D_param[d];
  float h = Hinit[(size_t)c * 32768 + d * 16 + s];
#pragma unroll 8
  for (int i = 0; i < TCHUNK; ++i) {
    int t = t0 + i;
    float dtv = dt[(size_t)t * 2048 + d];
    float xv = bf2f(x_ssm[(size_t)t * 2048 + d]);
    float Bv = x_dbl[t * 32 + s];
    float Cv = x_dbl[t * 32 + 16 + s];
    float dA = __expf(dtv * Aval);
    h = dA * h + Bv * dtv * xv;
    float yc = h * Cv;
    yc += __shfl_xor(yc, 1);
    yc += __shfl_xor(yc, 2);
    yc += __shfl_xor(yc, 4);
    yc += __shfl_xor(yc, 8);
    if (s == 0) {
      float y = yc + Dp * xv;
      float szv = bf2f(silu_z[(size_t)t * 2048 + d]);
      y_out[(size_t)t * 2048 + d] = f2bf(y * szv);
    }
  }
}

extern "C" void kernel_launch(void* const* d_in, const int* in_sizes, int n_in,
                              void* d_out, int out_size, void* d_ws, size_t ws_size,
                              hipStream_t stream) {
  const float* x      = (const float*)d_in[0];
  const float* W_in   = (const float*)d_in[1];
  const float* conv_w = (const float*)d_in[2];
  const float* conv_b = (const float*)d_in[3];
  const float* A_log  = (const float*)d_in[4];
  const float* D_par  = (const float*)d_in[5];
  const float* W_x    = (const float*)d_in[6];
  const float* W_dt   = (const float*)d_in[7];
  const float* b_dt   = (const float*)d_in[8];
  const float* W_out  = (const float*)d_in[9];
  float* out = (float*)d_out;

  char* ws = (char*)d_ws;
  unsigned short* xbf    = (unsigned short*)(ws + 0);                       // 4MB
  unsigned short* Winbf  = (unsigned short*)(ws + ((size_t)4 << 20));       // 8MB
  unsigned short* Wdtbf  = (unsigned short*)(ws + ((size_t)12 << 20));      // 8MB (freed after GEMM2)
  unsigned short* Woutbf = (unsigned short*)(ws + ((size_t)20 << 20));      // 4MB
  unsigned short* xz     = (unsigned short*)(ws + ((size_t)24 << 20));      // 16MB (freed after conv)
  unsigned short* xssm   = (unsigned short*)(ws + ((size_t)40 << 20));      // 8MB
  unsigned short* siluz  = (unsigned short*)(ws + ((size_t)48 << 20));      // 8MB
  float* dtf             = (float*)(ws + ((size_t)56 << 20));               // 16MB
  float* xdbl            = (float*)(ws + ((size_t)72 << 20));               // 256KB
  float* WxT             = (float*)(ws + ((size_t)72 << 20) + (256 << 10)); // 256KB
  unsigned short* yfin   = (unsigned short*)(ws + ((size_t)73 << 20));      // 8MB
  // scan scratch (reuses xz region, free after conv_silu; Wdtbf, free after GEMM2)
  float* Pbuf            = (float*)(ws + ((size_t)24 << 20));               // 8MB
  float* Hloc            = (float*)(ws + ((size_t)32 << 20));               // 8MB
  float* Hinit           = (float*)(ws + ((size_t)12 << 20));               // 8MB

  // fp32 -> bf16 converts
  cvt_f32_bf16<<<2048, 256, 0, stream>>>((const float4*)x, (ushort4*)xbf, (L_SEQ * DMODEL) / 4);
  cvt_f32_bf16<<<4096, 256, 0, stream>>>((const float4*)W_in, (ushort4*)Winbf, (2 * DINNER * DMODEL) / 4);
  cvt_f32_bf16<<<4096, 256, 0, stream>>>((const float4*)W_dt, (ushort4*)Wdtbf, (DINNER * DINNER) / 4);
  cvt_f32_bf16<<<2048, 256, 0, stream>>>((const float4*)W_out, (ushort4*)Woutbf, (DMODEL * DINNER) / 4);

  // GEMM1: xz[2048,4096] = x @ W_in^T  (bf16 out)
  gemm_bt<0><<<dim3(4096 / 128, L_SEQ / 128), 256, 0, stream>>>(
      xbf, Winbf, L_SEQ, 4096, DMODEL, nullptr, xz, nullptr);

  // conv + silu -> x_ssm; silu(z)
  conv_silu<<<(L_SEQ * DINNER) / 256, 256, 0, stream>>>(xz, conv_w, conv_b, xssm, siluz);

  // GEMM2: dt[2048,2048] = softplus(x_ssm @ W_dt^T + b_dt) (f32 out)
  gemm_bt<1><<<dim3(DINNER / 128, L_SEQ / 128), 256, 0, stream>>>(
      xssm, Wdtbf, L_SEQ, DINNER, DINNER, dtf, nullptr, b_dt);

  // x_dbl = x_ssm @ W_x^T  [2048,32]
  wx_transpose<<<(32 * DINNER) / 256, 256, 0, stream>>>(W_x, WxT);
  xdbl_kernel<<<L_SEQ / 4, 256, 0, stream>>>(xssm, WxT, xdbl);

  // chunked parallel scan -> y_final (gated) bf16
  scan_passA<<<(DINNER / 16) * NCHUNK, 256, 0, stream>>>(dtf, xssm, xdbl, A_log, Pbuf, Hloc);
  scan_passB<<<(DINNER * 16) / 256, 256, 0, stream>>>(Pbuf, Hloc, Hinit);
  scan_passC<<<(DINNER / 16) * NCHUNK, 256, 0, stream>>>(dtf, xssm, xdbl, A_log, D_par, siluz,
                                                         Hinit, yfin);

  // GEMM4: out[2048,1024] = y_final @ W_out^T + x (f32 out)
  gemm_bt<2><<<dim3(DMODEL / 128, L_SEQ / 128), 256, 0, stream>>>(
      yfin, Woutbf, L_SEQ, DMODEL, DINNER, out, nullptr, x);
}

// Round 3
// 347.065 us; speedup vs baseline: 4.7890x; 1.2848x over previous
//
#include <hip/hip_runtime.h>

#define L_SEQ 2048
#define DMODEL 1024
#define DINNER 2048
#define NCHUNK 128
#define TCHUNK 16

typedef __attribute__((ext_vector_type(8))) short bf16x8;
typedef __attribute__((ext_vector_type(4))) float f32x4;

__device__ __forceinline__ float bf2f(unsigned short u) {
  return __uint_as_float(((unsigned)u) << 16);
}
__device__ __forceinline__ unsigned short f2bf(float f) {
  unsigned u = __float_as_uint(f);
  return (unsigned short)((u + 0x7FFFu + ((u >> 16) & 1u)) >> 16);
}
__device__ __forceinline__ void gload_lds16(const void* g, void* l) {
  __builtin_amdgcn_global_load_lds(
      (const __attribute__((address_space(1))) void*)g,
      (__attribute__((address_space(3))) void*)l, 16, 0, 0);
}

// ---------------- fp32 -> bf16 convert (vectorized) ----------------
__global__ void cvt_f32_bf16(const float4* __restrict__ in, ushort4* __restrict__ out, int n4) {
  int i = blockIdx.x * blockDim.x + threadIdx.x;
  if (i >= n4) return;
  float4 v = in[i];
  ushort4 o;
  o.x = f2bf(v.x); o.y = f2bf(v.y); o.z = f2bf(v.z); o.w = f2bf(v.w);
  out[i] = o;
}

__global__ void zero_bf16(ushort4* __restrict__ out, int n4) {
  int i = blockIdx.x * blockDim.x + threadIdx.x;
  if (i >= n4) return;
  out[i] = ushort4{0, 0, 0, 0};
}

// ---------------- bf16 GEMM, C = A[M,K] * B[N,K]^T, m97 structure ----------------
// EPI: 0 = store bf16
//      2 = v + aux[row*N+col] -> f32
//      3 = col<2048: softplus(v+aux[col]) -> bf16 outb[row*2048+col]
//          2048<=col<2080: v -> outf[row*32+col-2048]   (x_dbl)
template <int EPI>
__global__ __launch_bounds__(256) void gemm_bt(
    const unsigned short* __restrict__ A, const unsigned short* __restrict__ B,
    int M, int N, int K,
    float* __restrict__ outf, unsigned short* __restrict__ outb,
    const float* __restrict__ aux) {
  __shared__ __align__(16) unsigned short As[128 * 32];
  __shared__ __align__(16) unsigned short Bs[128 * 32];
  const int tid = threadIdx.x;
  const int lane = tid & 63;
  const int wave = tid >> 6;
  const int wm = wave >> 1, wn = wave & 1;
  const int bm = blockIdx.y * 128, bn = blockIdx.x * 128;
  const int srow = tid >> 2, sc4 = tid & 3;

  const unsigned short* Ag = A + (size_t)(bm + srow) * K + sc4 * 8;
  const unsigned short* Bg = B + (size_t)(bn + srow) * K + sc4 * 8;
  unsigned short* AsW = &As[srow * 32 + sc4 * 8];
  unsigned short* BsW = &Bs[srow * 32 + sc4 * 8];

  f32x4 acc[4][4] = {};

  for (int k0 = 0; k0 < K; k0 += 32) {
    __syncthreads();
    gload_lds16(Ag + k0, AsW);
    gload_lds16(Ag + (size_t)64 * K + k0, AsW + 64 * 32);
    gload_lds16(Bg + k0, BsW);
    gload_lds16(Bg + (size_t)64 * K + k0, BsW + 64 * 32);
    __syncthreads();

    const int kz = (lane >> 4) * 8;
    const int r16 = lane & 15;
    bf16x8 a[4], b[4];
#pragma unroll
    for (int i = 0; i < 4; ++i)
      a[i] = *(const bf16x8*)&As[(wm * 64 + i * 16 + r16) * 32 + kz];
#pragma unroll
    for (int j = 0; j < 4; ++j)
      b[j] = *(const bf16x8*)&Bs[(wn * 64 + j * 16 + r16) * 32 + kz];
#pragma unroll
    for (int i = 0; i < 4; ++i)
#pragma unroll
      for (int j = 0; j < 4; ++j)
        acc[i][j] = __builtin_amdgcn_mfma_f32_16x16x32_bf16(a[i], b[j], acc[i][j], 0, 0, 0);
  }

  const int r16 = lane & 15;
  const int rq = lane >> 4;
#pragma unroll
  for (int i = 0; i < 4; ++i)
#pragma unroll
    for (int j = 0; j < 4; ++j)
#pragma unroll
      for (int r = 0; r < 4; ++r) {
        int row = bm + wm * 64 + i * 16 + rq * 4 + r;
        int col = bn + wn * 64 + j * 16 + r16;
        float v = acc[i][j][r];
        if (EPI == 0) {
          outb[(size_t)row * N + col] = f2bf(v);
        } else if (EPI == 2) {
          size_t off = (size_t)row * N + col;
          outf[off] = v + aux[off];
        } else {  // EPI == 3
          if (col < 2048) {
            float t = v + aux[col];
            float sp = (t > 15.f) ? t : log1pf(__expf(t));
            outb[(size_t)row * 2048 + col] = f2bf(sp);
          } else if (col < 2080) {
            outf[(size_t)row * 32 + (col - 2048)] = v;
          }
        }
      }
}

// ---------------- causal depthwise conv (D_CONV=4) + SiLU; also silu(z) ----------------
// one thread = 8 channels at one l
__global__ __launch_bounds__(256) void conv_silu8(
    const unsigned short* __restrict__ xz,
    const float* __restrict__ cw, const float* __restrict__ cb,
    unsigned short* __restrict__ x_ssm, unsigned short* __restrict__ sz_out) {
  int idx = blockIdx.x * 256 + threadIdx.x;  // 2048 l * 256 cgroups
  int l = idx >> 8, c0 = (idx & 255) * 8;
  float acc[8];
  float4 b0 = *(const float4*)(cb + c0);
  float4 b1 = *(const float4*)(cb + c0 + 4);
  acc[0] = b0.x; acc[1] = b0.y; acc[2] = b0.z; acc[3] = b0.w;
  acc[4] = b1.x; acc[5] = b1.y; acc[6] = b1.z; acc[7] = b1.w;
  float4 w[8];
#pragma unroll
  for (int j = 0; j < 8; ++j) w[j] = *(const float4*)(cw + (c0 + j) * 4);
#pragma unroll
  for (int k = 0; k < 4; ++k) {
    int lt = l - 3 + k;
    if (lt >= 0) {
      bf16x8 v = *(const bf16x8*)(xz + (size_t)lt * 4096 + c0);
      const float* wk = (const float*)w;
#pragma unroll
      for (int j = 0; j < 8; ++j)
        acc[j] = fmaf(bf2f((unsigned short)v[j]), wk[j * 4 + k], acc[j]);
    }
  }
  bf16x8 zr = *(const bf16x8*)(xz + (size_t)l * 4096 + 2048 + c0);
  bf16x8 ox, oz;
#pragma unroll
  for (int j = 0; j < 8; ++j) {
    float a = acc[j];
    ox[j] = (short)f2bf(a / (1.f + __expf(-a)));
    float zv = bf2f((unsigned short)zr[j]);
    oz[j] = (short)f2bf(zv / (1.f + __expf(-zv)));
  }
  *(bf16x8*)(x_ssm + (size_t)idx * 8) = ox;
  *(bf16x8*)(sz_out + (size_t)idx * 8) = oz;
}

// ---------------- chunked parallel scan, thread-per-channel (16 states in regs) ----------
__global__ __launch_bounds__(256) void scan_passA(
    const unsigned short* __restrict__ dtb, const unsigned short* __restrict__ x_ssm,
    const float* __restrict__ x_dbl, const float* __restrict__ A_log,
    float* __restrict__ Pout, float* __restrict__ Hout) {
  int tid = threadIdx.x;
  int c = blockIdx.x & (NCHUNK - 1), db = blockIdx.x >> 7;
  int d = db * 256 + tid;
  int t0 = c * TCHUNK;
  float Av[16];
  const float4* al4 = (const float4*)(A_log + d * 16);
#pragma unroll
  for (int q = 0; q < 4; ++q) {
    float4 a = al4[q];
    Av[q * 4 + 0] = -__expf(a.x); Av[q * 4 + 1] = -__expf(a.y);
    Av[q * 4 + 2] = -__expf(a.z); Av[q * 4 + 3] = -__expf(a.w);
  }
  float h[16];
#pragma unroll
  for (int s = 0; s < 16; ++s) h[s] = 0.f;
  float sum_dt = 0.f;
#pragma unroll 2
  for (int i = 0; i < TCHUNK; ++i) {
    int t = t0 + i;
    float dtv = bf2f(dtb[(size_t)t * 2048 + d]);
    float xv = bf2f(x_ssm[(size_t)t * 2048 + d]);
    float dtx = dtv * xv;
    sum_dt += dtv;
    const float* B = x_dbl + t * 32;  // wave-uniform -> scalar loads
#pragma unroll
    for (int s = 0; s < 16; ++s) {
      float dA = __expf(dtv * Av[s]);
      h[s] = fmaf(dA, h[s], B[s] * dtx);
    }
  }
  float* Ho = Hout + (size_t)c * 32768 + d * 16;
  float* Po = Pout + (size_t)c * 32768 + d * 16;
#pragma unroll
  for (int s = 0; s < 16; ++s) Ho[s] = h[s];
#pragma unroll
  for (int s = 0; s < 16; ++s) Po[s] = __expf(sum_dt * Av[s]);
}

// Pass B: serial combine; rewrites P buffer in-place with chunk-entry states (Hinit).
__global__ __launch_bounds__(256) void scan_passB(
    float* __restrict__ P, const float* __restrict__ Hloc) {
  int i = blockIdx.x * 256 + threadIdx.x;  // 32768 (d,s)
  float h = 0.f;
  for (int c = 0; c < NCHUNK; ++c) {
    size_t o = (size_t)c * 32768 + i;
    float p = P[o];
    float hl = Hloc[o];
    P[o] = h;
    h = fmaf(p, h, hl);
  }
}

// Pass C: re-run chunk from entry state; emit gated y (bf16).
__global__ __launch_bounds__(256) void scan_passC(
    const unsigned short* __restrict__ dtb, const unsigned short* __restrict__ x_ssm,
    const float* __restrict__ x_dbl, const float* __restrict__ A_log,
    const float* __restrict__ D_param, const unsigned short* __restrict__ silu_z,
    const float* __restrict__ Hinit, unsigned short* __restrict__ y_out) {
  int tid = threadIdx.x;
  int c = blockIdx.x & (NCHUNK - 1), db = blockIdx.x >> 7;
  int d = db * 256 + tid;
  int t0 = c * TCHUNK;
  float Av[16];
  const float4* al4 = (const float4*)(A_log + d * 16);
#pragma unroll
  for (int q = 0; q < 4; ++q) {
    float4 a = al4[q];
    Av[q * 4 + 0] = -__expf(a.x); Av[q * 4 + 1] = -__expf(a.y);
    Av[q * 4 + 2] = -__expf(a.z); Av[q * 4 + 3] = -__expf(a.w);
  }
  float Dp = D_param[d];
  float h[16];
  const float4* hi4 = (const float4*)(Hinit + (size_t)c * 32768 + d * 16);
#pragma unroll
  for (int q = 0; q < 4; ++q) {
    float4 v = hi4[q];
    h[q * 4 + 0] = v.x; h[q * 4 + 1] = v.y; h[q * 4 + 2] = v.z; h[q * 4 + 3] = v.w;
  }
#pragma unroll 2
  for (int i = 0; i < TCHUNK; ++i) {
    int t = t0 + i;
    float dtv = bf2f(dtb[(size_t)t * 2048 + d]);
    float xv = bf2f(x_ssm[(size_t)t * 2048 + d]);
    float dtx = dtv * xv;
    const float* B = x_dbl + t * 32;       // uniform
    const float* C = x_dbl + t * 32 + 16;  // uniform
    float y = 0.f;
#pragma unroll
    for (int s = 0; s < 16; ++s) {
      float dA = __expf(dtv * Av[s]);
      h[s] = fmaf(dA, h[s], B[s] * dtx);
      y = fmaf(h[s], C[s], y);
    }
    float szv = bf2f(silu_z[(size_t)t * 2048 + d]);
    y_out[(size_t)t * 2048 + d] = f2bf((y + Dp * xv) * szv);
  }
}

extern "C" void kernel_launch(void* const* d_in, const int* in_sizes, int n_in,
                              void* d_out, int out_size, void* d_ws, size_t ws_size,
                              hipStream_t stream) {
  const float* x      = (const float*)d_in[0];
  const float* W_in   = (const float*)d_in[1];
  const float* conv_w = (const float*)d_in[2];
  const float* conv_b = (const float*)d_in[3];
  const float* A_log  = (const float*)d_in[4];
  const float* D_par  = (const float*)d_in[5];
  const float* W_x    = (const float*)d_in[6];
  const float* W_dt   = (const float*)d_in[7];
  const float* b_dt   = (const float*)d_in[8];
  const float* W_out  = (const float*)d_in[9];
  float* out = (float*)d_out;

  char* ws = (char*)d_ws;
  unsigned short* xbf    = (unsigned short*)(ws + 0);                    // 4MB
  unsigned short* Winbf  = (unsigned short*)(ws + ((size_t)4 << 20));    // 8MB
  unsigned short* Wcomb  = (unsigned short*)(ws + ((size_t)12 << 20));   // 8.5MB [2176][2048]
  unsigned short* Woutbf = (unsigned short*)(ws + ((size_t)21 << 20));   // 4MB
  unsigned short* xz     = (unsigned short*)(ws + ((size_t)25 << 20));   // 16MB (free after conv)
  unsigned short* xssm   = (unsigned short*)(ws + ((size_t)41 << 20));   // 8MB
  unsigned short* siluz  = (unsigned short*)(ws + ((size_t)49 << 20));   // 8MB
  unsigned short* dtb    = (unsigned short*)(ws + ((size_t)57 << 20));   // 8MB (bf16 dt)
  float* xdbl            = (float*)(ws + ((size_t)65 << 20));            // 256KB
  unsigned short* yfin   = (unsigned short*)(ws + ((size_t)66 << 20));   // 8MB
  float* Pbuf            = (float*)(ws + ((size_t)25 << 20));            // 16MB (alias xz; also Hinit)
  float* Hloc            = (float*)(ws + ((size_t)4 << 20));             // 16MB (alias Winbf+Wcomb, free after GEMM2)

  // fp32 -> bf16 converts
  cvt_f32_bf16<<<2048, 256, 0, stream>>>((const float4*)x, (ushort4*)xbf, (L_SEQ * DMODEL) / 4);
  cvt_f32_bf16<<<4096, 256, 0, stream>>>((const float4*)W_in, (ushort4*)Winbf, (2 * DINNER * DMODEL) / 4);
  // Wcomb rows 0..2047 = W_dt, rows 2048..2079 = W_x, rows 2080..2175 = 0
  cvt_f32_bf16<<<4096, 256, 0, stream>>>((const float4*)W_dt, (ushort4*)Wcomb, (DINNER * DINNER) / 4);
  cvt_f32_bf16<<<64, 256, 0, stream>>>((const float4*)W_x, (ushort4*)(Wcomb + (size_t)2048 * 2048),
                                       (32 * DINNER) / 4);
  zero_bf16<<<192, 256, 0, stream>>>((ushort4*)(Wcomb + (size_t)2080 * 2048), (96 * DINNER) / 4);
  cvt_f32_bf16<<<2048, 256, 0, stream>>>((const float4*)W_out, (ushort4*)Woutbf, (DMODEL * DINNER) / 4);

  // GEMM1: xz[2048,4096] = x @ W_in^T  (bf16 out)
  gemm_bt<0><<<dim3(4096 / 128, L_SEQ / 128), 256, 0, stream>>>(
      xbf, Winbf, L_SEQ, 4096, DMODEL, nullptr, xz, nullptr);

  // conv + silu -> x_ssm; silu(z)
  conv_silu8<<<2048, 256, 0, stream>>>(xz, conv_w, conv_b, xssm, siluz);

  // GEMM2 (fused): dt bf16 [2048,2048] (softplus) + x_dbl f32 [2048,32]
  gemm_bt<3><<<dim3(2176 / 128, L_SEQ / 128), 256, 0, stream>>>(
      xssm, Wcomb, L_SEQ, 2176, DINNER, xdbl, dtb, b_dt);

  // chunked parallel scan
  scan_passA<<<NCHUNK * (DINNER / 256), 256, 0, stream>>>(dtb, xssm, xdbl, A_log, Pbuf, Hloc);
  scan_passB<<<(DINNER * 16) / 256, 256, 0, stream>>>(Pbuf, Hloc);
  scan_passC<<<NCHUNK * (DINNER / 256), 256, 0, stream>>>(dtb, xssm, xdbl, A_log, D_par, siluz,
                                                          Pbuf, yfin);

  // GEMM4: out[2048,1024] = y_final @ W_out^T + x (f32 out)
  gemm_bt<2><<<dim3(DMODEL / 128, L_SEQ / 128), 256, 0, stream>>>(
      yfin, Woutbf, L_SEQ, DMODEL, DINNER, out, nullptr, x);
}

// Round 4
// 321.769 us; speedup vs baseline: 5.1655x; 1.0786x over previous
//
#include <hip/hip_runtime.h>

#define L_SEQ 2048
#define DMODEL 1024
#define DINNER 2048
#define NCHUNK 128
#define TCHUNK 16

typedef __attribute__((ext_vector_type(8))) short bf16x8;
typedef __attribute__((ext_vector_type(4))) float f32x4;

__device__ __forceinline__ float bf2f(unsigned short u) {
  return __uint_as_float(((unsigned)u) << 16);
}
__device__ __forceinline__ unsigned short f2bf(float f) {
  unsigned u = __float_as_uint(f);
  return (unsigned short)((u + 0x7FFFu + ((u >> 16) & 1u)) >> 16);
}
__device__ __forceinline__ void gload_lds16(const void* g, void* l) {
  __builtin_amdgcn_global_load_lds(
      (const __attribute__((address_space(1))) void*)g,
      (__attribute__((address_space(3))) void*)l, 16, 0, 0);
}

// ---------------- fp32 -> bf16 convert (vectorized) ----------------
__global__ void cvt_f32_bf16(const float4* __restrict__ in, ushort4* __restrict__ out, int n4) {
  int i = blockIdx.x * blockDim.x + threadIdx.x;
  if (i >= n4) return;
  float4 v = in[i];
  ushort4 o;
  o.x = f2bf(v.x); o.y = f2bf(v.y); o.z = f2bf(v.z); o.w = f2bf(v.w);
  out[i] = o;
}

__global__ void zero_bf16(ushort4* __restrict__ out, int n4) {
  int i = blockIdx.x * blockDim.x + threadIdx.x;
  if (i >= n4) return;
  out[i] = ushort4{0, 0, 0, 0};
}

// ---------------- bf16 GEMM, C = A[M,K] * B[N,K]^T, 2-phase double-buffered ----------
// 1D grid (nwg % 8 == 0), XCD chunk swizzle. ksplit in {1,2}: K-range split, EPI 4
// stores f32 partials at outf[ks*M*N + ...].
// EPI: 0 = store bf16
//      3 = col<2048: softplus(v+aux[col]) -> bf16 outb; 2048<=col<2080: v -> outf[row*32+col-2048]
//      4 = partial f32 store
template <int EPI>
__global__ __launch_bounds__(256) void gemm_bt2(
    const unsigned short* __restrict__ A, const unsigned short* __restrict__ B,
    int M, int N, int K, int nx, int ksplit,
    float* __restrict__ outf, unsigned short* __restrict__ outb,
    const float* __restrict__ aux) {
  __shared__ __align__(16) unsigned short As[2 * 128 * 32];
  __shared__ __align__(16) unsigned short Bs[2 * 128 * 32];
  const int tid = threadIdx.x;
  const int lane = tid & 63;
  const int wave = tid >> 6;
  const int wm = wave >> 1, wn = wave & 1;

  // XCD-aware bijective chunk swizzle (nwg % 8 == 0)
  const int nwg = gridDim.x;
  const int wg = blockIdx.x;
  const int swz = (wg & 7) * (nwg >> 3) + (wg >> 3);
  const int tiles = nwg / ksplit;
  const int ks = swz / tiles;
  const int t = swz - ks * tiles;
  const int bx = t % nx, by = t / nx;
  const int bm = by * 128, bn = bx * 128;
  const int Ks = K / ksplit;
  const int kbeg = ks * Ks, kend = ks * Ks + Ks;

  const int srow = tid >> 2, sc4 = tid & 3;
  const unsigned short* Ag = A + (size_t)(bm + srow) * K + sc4 * 8;
  const unsigned short* Bg = B + (size_t)(bn + srow) * K + sc4 * 8;
  unsigned short* AsW = &As[srow * 32 + sc4 * 8];
  unsigned short* BsW = &Bs[srow * 32 + sc4 * 8];

  auto STAGE = [&](int buf, int k0) {
    gload_lds16(Ag + k0, AsW + buf * 4096);
    gload_lds16(Ag + (size_t)64 * K + k0, AsW + buf * 4096 + 64 * 32);
    gload_lds16(Bg + k0, BsW + buf * 4096);
    gload_lds16(Bg + (size_t)64 * K + k0, BsW + buf * 4096 + 64 * 32);
  };

  f32x4 acc[4][4] = {};

  STAGE(0, kbeg);
  __syncthreads();

  const int kz = (lane >> 4) * 8;
  const int r16 = lane & 15;

  for (int k0 = kbeg; k0 < kend; k0 += 32) {
    int cur = ((k0 - kbeg) >> 5) & 1;
    if (k0 + 32 < kend) STAGE(cur ^ 1, k0 + 32);

    bf16x8 a[4], b[4];
#pragma unroll
    for (int i = 0; i < 4; ++i)
      a[i] = *(const bf16x8*)&As[cur * 4096 + (wm * 64 + i * 16 + r16) * 32 + kz];
#pragma unroll
    for (int j = 0; j < 4; ++j)
      b[j] = *(const bf16x8*)&Bs[cur * 4096 + (wn * 64 + j * 16 + r16) * 32 + kz];
#pragma unroll
    for (int i = 0; i < 4; ++i)
#pragma unroll
      for (int j = 0; j < 4; ++j)
        acc[i][j] = __builtin_amdgcn_mfma_f32_16x16x32_bf16(a[i], b[j], acc[i][j], 0, 0, 0);

    __syncthreads();
  }

  const int rq = lane >> 4;
#pragma unroll
  for (int i = 0; i < 4; ++i)
#pragma unroll
    for (int j = 0; j < 4; ++j)
#pragma unroll
      for (int r = 0; r < 4; ++r) {
        int row = bm + wm * 64 + i * 16 + rq * 4 + r;
        int col = bn + wn * 64 + j * 16 + r16;
        float v = acc[i][j][r];
        if (EPI == 0) {
          outb[(size_t)row * N + col] = f2bf(v);
        } else if (EPI == 3) {
          if (col < 2048) {
            float tt = v + aux[col];
            float sp = (tt > 15.f) ? tt : log1pf(__expf(tt));
            outb[(size_t)row * 2048 + col] = f2bf(sp);
          } else if (col < 2080) {
            outf[(size_t)row * 32 + (col - 2048)] = v;
          }
        } else {  // EPI == 4: split-K partial
          outf[(size_t)ks * M * N + (size_t)row * N + col] = v;
        }
      }
}

// ---------------- split-K reduce + residual add ----------------
__global__ void reduce_addx(const float4* __restrict__ p, const float4* __restrict__ x,
                            float4* __restrict__ out, int n4) {
  int i = blockIdx.x * 256 + threadIdx.x;
  if (i >= n4) return;
  float4 a = p[i], b = p[n4 + i], c = x[i];
  float4 o;
  o.x = a.x + b.x + c.x; o.y = a.y + b.y + c.y;
  o.z = a.z + b.z + c.z; o.w = a.w + b.w + c.w;
  out[i] = o;
}

// ---------------- causal depthwise conv (D_CONV=4) + SiLU; also silu(z) ----------------
__global__ __launch_bounds__(256) void conv_silu8(
    const unsigned short* __restrict__ xz,
    const float* __restrict__ cw, const float* __restrict__ cb,
    unsigned short* __restrict__ x_ssm, unsigned short* __restrict__ sz_out) {
  int idx = blockIdx.x * 256 + threadIdx.x;  // 2048 l * 256 cgroups
  int l = idx >> 8, c0 = (idx & 255) * 8;
  float acc[8];
  float4 b0 = *(const float4*)(cb + c0);
  float4 b1 = *(const float4*)(cb + c0 + 4);
  acc[0] = b0.x; acc[1] = b0.y; acc[2] = b0.z; acc[3] = b0.w;
  acc[4] = b1.x; acc[5] = b1.y; acc[6] = b1.z; acc[7] = b1.w;
  float4 w[8];
#pragma unroll
  for (int j = 0; j < 8; ++j) w[j] = *(const float4*)(cw + (c0 + j) * 4);
#pragma unroll
  for (int k = 0; k < 4; ++k) {
    int lt = l - 3 + k;
    if (lt >= 0) {
      bf16x8 v = *(const bf16x8*)(xz + (size_t)lt * 4096 + c0);
      const float* wk = (const float*)w;
#pragma unroll
      for (int j = 0; j < 8; ++j)
        acc[j] = fmaf(bf2f((unsigned short)v[j]), wk[j * 4 + k], acc[j]);
    }
  }
  bf16x8 zr = *(const bf16x8*)(xz + (size_t)l * 4096 + 2048 + c0);
  bf16x8 ox, oz;
#pragma unroll
  for (int j = 0; j < 8; ++j) {
    float a = acc[j];
    ox[j] = (short)f2bf(a / (1.f + __expf(-a)));
    float zv = bf2f((unsigned short)zr[j]);
    oz[j] = (short)f2bf(zv / (1.f + __expf(-zv)));
  }
  *(bf16x8*)(x_ssm + (size_t)idx * 8) = ox;
  *(bf16x8*)(sz_out + (size_t)idx * 8) = oz;
}

// ---------------- chunked parallel scan, thread-per-channel (16 states in regs) ----------
__global__ __launch_bounds__(256) void scan_passA(
    const unsigned short* __restrict__ dtb, const unsigned short* __restrict__ x_ssm,
    const float* __restrict__ x_dbl, const float* __restrict__ A_log,
    float* __restrict__ Pout, float* __restrict__ Hout) {
  int tid = threadIdx.x;
  int c = blockIdx.x & (NCHUNK - 1), db = blockIdx.x >> 7;
  int d = db * 256 + tid;
  int t0 = c * TCHUNK;
  float Av[16];
  const float4* al4 = (const float4*)(A_log + d * 16);
#pragma unroll
  for (int q = 0; q < 4; ++q) {
    float4 a = al4[q];
    Av[q * 4 + 0] = -__expf(a.x); Av[q * 4 + 1] = -__expf(a.y);
    Av[q * 4 + 2] = -__expf(a.z); Av[q * 4 + 3] = -__expf(a.w);
  }
  float h[16];
#pragma unroll
  for (int s = 0; s < 16; ++s) h[s] = 0.f;
  float sum_dt = 0.f;
#pragma unroll 2
  for (int i = 0; i < TCHUNK; ++i) {
    int t = t0 + i;
    float dtv = bf2f(dtb[(size_t)t * 2048 + d]);
    float xv = bf2f(x_ssm[(size_t)t * 2048 + d]);
    float dtx = dtv * xv;
    sum_dt += dtv;
    const float* B = x_dbl + t * 32;  // wave-uniform -> scalar loads
#pragma unroll
    for (int s = 0; s < 16; ++s) {
      float dA = __expf(dtv * Av[s]);
      h[s] = fmaf(dA, h[s], B[s] * dtx);
    }
  }
  float* Ho = Hout + (size_t)c * 32768 + d * 16;
  float* Po = Pout + (size_t)c * 32768 + d * 16;
#pragma unroll
  for (int s = 0; s < 16; ++s) Ho[s] = h[s];
#pragma unroll
  for (int s = 0; s < 16; ++s) Po[s] = __expf(sum_dt * Av[s]);
}

// Pass B: serial combine; rewrites P buffer in-place with chunk-entry states (Hinit).
__global__ __launch_bounds__(256) void scan_passB(
    float* __restrict__ P, const float* __restrict__ Hloc) {
  int i = blockIdx.x * 256 + threadIdx.x;  // 32768 (d,s)
  float h = 0.f;
  for (int c = 0; c < NCHUNK; ++c) {
    size_t o = (size_t)c * 32768 + i;
    float p = P[o];
    float hl = Hloc[o];
    P[o] = h;
    h = fmaf(p, h, hl);
  }
}

// Pass C: re-run chunk from entry state; emit gated y (bf16).
__global__ __launch_bounds__(256) void scan_passC(
    const unsigned short* __restrict__ dtb, const unsigned short* __restrict__ x_ssm,
    const float* __restrict__ x_dbl, const float* __restrict__ A_log,
    const float* __restrict__ D_param, const unsigned short* __restrict__ silu_z,
    const float* __restrict__ Hinit, unsigned short* __restrict__ y_out) {
  int tid = threadIdx.x;
  int c = blockIdx.x & (NCHUNK - 1), db = blockIdx.x >> 7;
  int d = db * 256 + tid;
  int t0 = c * TCHUNK;
  float Av[16];
  const float4* al4 = (const float4*)(A_log + d * 16);
#pragma unroll
  for (int q = 0; q < 4; ++q) {
    float4 a = al4[q];
    Av[q * 4 + 0] = -__expf(a.x); Av[q * 4 + 1] = -__expf(a.y);
    Av[q * 4 + 2] = -__expf(a.z); Av[q * 4 + 3] = -__expf(a.w);
  }
  float Dp = D_param[d];
  float h[16];
  const float4* hi4 = (const float4*)(Hinit + (size_t)c * 32768 + d * 16);
#pragma unroll
  for (int q = 0; q < 4; ++q) {
    float4 v = hi4[q];
    h[q * 4 + 0] = v.x; h[q * 4 + 1] = v.y; h[q * 4 + 2] = v.z; h[q * 4 + 3] = v.w;
  }
#pragma unroll 2
  for (int i = 0; i < TCHUNK; ++i) {
    int t = t0 + i;
    float dtv = bf2f(dtb[(size_t)t * 2048 + d]);
    float xv = bf2f(x_ssm[(size_t)t * 2048 + d]);
    float dtx = dtv * xv;
    const float* B = x_dbl + t * 32;       // uniform
    const float* C = x_dbl + t * 32 + 16;  // uniform
    float y = 0.f;
#pragma unroll
    for (int s = 0; s < 16; ++s) {
      float dA = __expf(dtv * Av[s]);
      h[s] = fmaf(dA, h[s], B[s] * dtx);
      y = fmaf(h[s], C[s], y);
    }
    float szv = bf2f(silu_z[(size_t)t * 2048 + d]);
    y_out[(size_t)t * 2048 + d] = f2bf((y + Dp * xv) * szv);
  }
}

extern "C" void kernel_launch(void* const* d_in, const int* in_sizes, int n_in,
                              void* d_out, int out_size, void* d_ws, size_t ws_size,
                              hipStream_t stream) {
  const float* x      = (const float*)d_in[0];
  const float* W_in   = (const float*)d_in[1];
  const float* conv_w = (const float*)d_in[2];
  const float* conv_b = (const float*)d_in[3];
  const float* A_log  = (const float*)d_in[4];
  const float* D_par  = (const float*)d_in[5];
  const float* W_x    = (const float*)d_in[6];
  const float* W_dt   = (const float*)d_in[7];
  const float* b_dt   = (const float*)d_in[8];
  const float* W_out  = (const float*)d_in[9];
  float* out = (float*)d_out;

  char* ws = (char*)d_ws;
  unsigned short* xbf    = (unsigned short*)(ws + 0);                    // 4MB
  unsigned short* Winbf  = (unsigned short*)(ws + ((size_t)4 << 20));    // 8MB
  unsigned short* Wcomb  = (unsigned short*)(ws + ((size_t)12 << 20));   // 8.5MB [2176][2048]
  unsigned short* Woutbf = (unsigned short*)(ws + ((size_t)21 << 20));   // 4MB
  unsigned short* xz     = (unsigned short*)(ws + ((size_t)25 << 20));   // 16MB (free after conv)
  unsigned short* xssm   = (unsigned short*)(ws + ((size_t)41 << 20));   // 8MB (free after passC)
  unsigned short* siluz  = (unsigned short*)(ws + ((size_t)49 << 20));   // 8MB (free after passC)
  unsigned short* dtb    = (unsigned short*)(ws + ((size_t)57 << 20));   // 8MB (bf16 dt)
  float* xdbl            = (float*)(ws + ((size_t)65 << 20));            // 256KB
  unsigned short* yfin   = (unsigned short*)(ws + ((size_t)66 << 20));   // 8MB
  float* Pbuf            = (float*)(ws + ((size_t)25 << 20));            // 16MB (alias xz)
  float* Hloc            = (float*)(ws + ((size_t)4 << 20));             // 16MB (alias Winbf+Wcomb)
  float* part            = (float*)(ws + ((size_t)41 << 20));            // 16MB (alias xssm+siluz)

  // fp32 -> bf16 converts
  cvt_f32_bf16<<<2048, 256, 0, stream>>>((const float4*)x, (ushort4*)xbf, (L_SEQ * DMODEL) / 4);
  cvt_f32_bf16<<<4096, 256, 0, stream>>>((const float4*)W_in, (ushort4*)Winbf, (2 * DINNER * DMODEL) / 4);
  // Wcomb rows 0..2047 = W_dt, rows 2048..2079 = W_x, rows 2080..2175 = 0
  cvt_f32_bf16<<<4096, 256, 0, stream>>>((const float4*)W_dt, (ushort4*)Wcomb, (DINNER * DINNER) / 4);
  cvt_f32_bf16<<<64, 256, 0, stream>>>((const float4*)W_x, (ushort4*)(Wcomb + (size_t)2048 * 2048),
                                       (32 * DINNER) / 4);
  zero_bf16<<<192, 256, 0, stream>>>((ushort4*)(Wcomb + (size_t)2080 * 2048), (96 * DINNER) / 4);
  cvt_f32_bf16<<<2048, 256, 0, stream>>>((const float4*)W_out, (ushort4*)Woutbf, (DMODEL * DINNER) / 4);

  // GEMM1: xz[2048,4096] = x @ W_in^T  (bf16 out) — 512 blocks
  gemm_bt2<0><<<512, 256, 0, stream>>>(xbf, Winbf, L_SEQ, 4096, DMODEL, 32, 1,
                                       nullptr, xz, nullptr);

  // conv + silu -> x_ssm; silu(z)
  conv_silu8<<<2048, 256, 0, stream>>>(xz, conv_w, conv_b, xssm, siluz);

  // GEMM2 (fused): dt bf16 [2048,2048] (softplus) + x_dbl f32 [2048,32] — 272 blocks
  gemm_bt2<3><<<272, 256, 0, stream>>>(xssm, Wcomb, L_SEQ, 2176, DINNER, 17, 1,
                                       xdbl, dtb, b_dt);

  // chunked parallel scan
  scan_passA<<<NCHUNK * (DINNER / 256), 256, 0, stream>>>(dtb, xssm, xdbl, A_log, Pbuf, Hloc);
  scan_passB<<<(DINNER * 16) / 256, 256, 0, stream>>>(Pbuf, Hloc);
  scan_passC<<<NCHUNK * (DINNER / 256), 256, 0, stream>>>(dtb, xssm, xdbl, A_log, D_par, siluz,
                                                          Pbuf, yfin);

  // GEMM4: split-K x2 partials [2,2048,1024] f32 — 256 blocks
  gemm_bt2<4><<<256, 256, 0, stream>>>(yfin, Woutbf, L_SEQ, DMODEL, DINNER, 8, 2,
                                       part, nullptr, nullptr);
  // out = p0 + p1 + x
  reduce_addx<<<(L_SEQ * DMODEL / 4 + 255) / 256, 256, 0, stream>>>(
      (const float4*)part, (const float4*)x, (float4*)out, L_SEQ * DMODEL / 4);
}

// Round 5
// 319.978 us; speedup vs baseline: 5.1944x; 1.0056x over previous
//
#include <hip/hip_runtime.h>

#define L_SEQ 2048
#define DMODEL 1024
#define DINNER 2048
#define NCHUNK 128
#define TCHUNK 16

typedef __attribute__((ext_vector_type(8))) short bf16x8;
typedef __attribute__((ext_vector_type(4))) float f32x4;

__device__ __forceinline__ float bf2f(unsigned short u) {
  return __uint_as_float(((unsigned)u) << 16);
}
__device__ __forceinline__ unsigned short f2bf(float f) {
  unsigned u = __float_as_uint(f);
  return (unsigned short)((u + 0x7FFFu + ((u >> 16) & 1u)) >> 16);
}
__device__ __forceinline__ void gload_lds16(const void* g, void* l) {
  __builtin_amdgcn_global_load_lds(
      (const __attribute__((address_space(1))) void*)g,
      (__attribute__((address_space(3))) void*)l, 16, 0, 0);
}

// ---------------- fp32 -> bf16 convert (vectorized) ----------------
__global__ void cvt_f32_bf16(const float4* __restrict__ in, ushort4* __restrict__ out, int n4) {
  int i = blockIdx.x * blockDim.x + threadIdx.x;
  if (i >= n4) return;
  float4 v = in[i];
  ushort4 o;
  o.x = f2bf(v.x); o.y = f2bf(v.y); o.z = f2bf(v.z); o.w = f2bf(v.w);
  out[i] = o;
}

__global__ void zero_bf16(ushort4* __restrict__ out, int n4) {
  int i = blockIdx.x * blockDim.x + threadIdx.x;
  if (i >= n4) return;
  out[i] = ushort4{0, 0, 0, 0};
}

// ---------------- bf16 GEMM, C = A[M,K] * B[N,K]^T ----------------
// Triple-buffered LDS pipeline with counted vmcnt (T3+T4) + source-swizzled staging (T2).
// 1D grid (nwg % 8 == 0), XCD chunk swizzle. ksplit in {1,2}.
// EPI: 0 = store bf16
//      3 = col<2048: softplus(v+aux[col]) -> bf16 outb; 2048<=col<2080: v -> outf[row*32+col-2048]
//      4 = partial f32 store at outf[ks*M*N + row*N + col]
template <int EPI>
__global__ __launch_bounds__(256) void gemm_bt3(
    const unsigned short* __restrict__ A, const unsigned short* __restrict__ B,
    int M, int N, int K, int nx, int ksplit,
    float* __restrict__ outf, unsigned short* __restrict__ outb,
    const float* __restrict__ aux) {
  __shared__ __align__(16) unsigned short As[3 * 128 * 32];
  __shared__ __align__(16) unsigned short Bs[3 * 128 * 32];
  const int tid = threadIdx.x;
  const int lane = tid & 63;
  const int wave = tid >> 6;
  const int wm = wave >> 1, wn = wave & 1;

  // XCD-aware bijective chunk swizzle (nwg % 8 == 0)
  const int nwg = gridDim.x;
  const int wg = blockIdx.x;
  const int swzb = (wg & 7) * (nwg >> 3) + (wg >> 3);
  const int tiles = nwg / ksplit;
  const int ks = swzb / tiles;
  const int t = swzb - ks * tiles;
  const int bx = t % nx, by = t / nx;
  const int bm = by * 128, bn = bx * 128;
  const int Ks = K / ksplit;
  const int kbeg = ks * Ks;
  const int nk = Ks >> 5;

  // staging: thread tid -> (row = tid>>2, colgroup = tid&3); LDS dest linear (tid*16B),
  // global source col-group permuted: c' = c ^ ((row>>1)&3)  [T2 via pre-swizzled source]
  const int srow = tid >> 2, sc4 = tid & 3;
  const int scp = sc4 ^ ((srow >> 1) & 3);
  const unsigned short* Ag = A + (size_t)(bm + srow) * K + scp * 8;
  const unsigned short* Bg = B + (size_t)(bn + srow) * K + scp * 8;
  unsigned short* AsW = &As[srow * 32 + sc4 * 8];
  unsigned short* BsW = &Bs[srow * 32 + sc4 * 8];

  auto STAGE = [&](int buf, int k0) {
    gload_lds16(Ag + k0, AsW + buf * 4096);
    gload_lds16(Ag + (size_t)64 * K + k0, AsW + buf * 4096 + 64 * 32);
    gload_lds16(Bg + k0, BsW + buf * 4096);
    gload_lds16(Bg + (size_t)64 * K + k0, BsW + buf * 4096 + 64 * 32);
  };

  f32x4 acc[4][4] = {};

  const int g = lane >> 4;
  const int r16 = lane & 15;
  // read-side swizzle: slot = g ^ ((row>>1)&3); row = w*64 + i*16 + r16 -> ((row>>1)&3)
  // is i-independent => per-lane constant:
  const int sw = (g ^ ((r16 >> 1) & 3)) * 8;

  STAGE(0, kbeg);
  STAGE(1, kbeg + 32);
  int cur = 0, stg = 2;

  for (int i = 0; i < nk; ++i) {
    if (i < nk - 1) {
      asm volatile("s_waitcnt vmcnt(4)" ::: "memory");
    } else {
      asm volatile("s_waitcnt vmcnt(0)" ::: "memory");
    }
    __builtin_amdgcn_s_barrier();
    asm volatile("" ::: "memory");
    if (i + 2 < nk) {
      STAGE(stg, kbeg + (i + 2) * 32);
      stg = (stg == 2) ? 0 : stg + 1;
    }

    bf16x8 a[4], b[4];
#pragma unroll
    for (int ii = 0; ii < 4; ++ii)
      a[ii] = *(const bf16x8*)&As[cur * 4096 + (wm * 64 + ii * 16 + r16) * 32 + sw];
#pragma unroll
    for (int j = 0; j < 4; ++j)
      b[j] = *(const bf16x8*)&Bs[cur * 4096 + (wn * 64 + j * 16 + r16) * 32 + sw];
#pragma unroll
    for (int ii = 0; ii < 4; ++ii)
#pragma unroll
      for (int j = 0; j < 4; ++j)
        acc[ii][j] = __builtin_amdgcn_mfma_f32_16x16x32_bf16(a[ii], b[j], acc[ii][j], 0, 0, 0);

    cur = (cur == 2) ? 0 : cur + 1;
  }

  const int rq = lane >> 4;
#pragma unroll
  for (int i = 0; i < 4; ++i)
#pragma unroll
    for (int j = 0; j < 4; ++j)
#pragma unroll
      for (int r = 0; r < 4; ++r) {
        int row = bm + wm * 64 + i * 16 + rq * 4 + r;
        int col = bn + wn * 64 + j * 16 + r16;
        float v = acc[i][j][r];
        if (EPI == 0) {
          outb[(size_t)row * N + col] = f2bf(v);
        } else if (EPI == 3) {
          if (col < 2048) {
            float tt = v + aux[col];
            float sp = (tt > 15.f) ? tt : log1pf(__expf(tt));
            outb[(size_t)row * 2048 + col] = f2bf(sp);
          } else if (col < 2080) {
            outf[(size_t)row * 32 + (col - 2048)] = v;
          }
        } else {  // EPI == 4: split-K partial
          outf[(size_t)ks * M * N + (size_t)row * N + col] = v;
        }
      }
}

// ---------------- split-K reduce + residual add ----------------
__global__ void reduce_addx(const float4* __restrict__ p, const float4* __restrict__ x,
                            float4* __restrict__ out, int n4) {
  int i = blockIdx.x * 256 + threadIdx.x;
  if (i >= n4) return;
  float4 a = p[i], b = p[n4 + i], c = x[i];
  float4 o;
  o.x = a.x + b.x + c.x; o.y = a.y + b.y + c.y;
  o.z = a.z + b.z + c.z; o.w = a.w + b.w + c.w;
  out[i] = o;
}

// ---------------- causal depthwise conv (D_CONV=4) + SiLU; also silu(z) ----------------
__global__ __launch_bounds__(256) void conv_silu8(
    const unsigned short* __restrict__ xz,
    const float* __restrict__ cw, const float* __restrict__ cb,
    unsigned short* __restrict__ x_ssm, unsigned short* __restrict__ sz_out) {
  int idx = blockIdx.x * 256 + threadIdx.x;  // 2048 l * 256 cgroups
  int l = idx >> 8, c0 = (idx & 255) * 8;
  float acc[8];
  float4 b0 = *(const float4*)(cb + c0);
  float4 b1 = *(const float4*)(cb + c0 + 4);
  acc[0] = b0.x; acc[1] = b0.y; acc[2] = b0.z; acc[3] = b0.w;
  acc[4] = b1.x; acc[5] = b1.y; acc[6] = b1.z; acc[7] = b1.w;
  float4 w[8];
#pragma unroll
  for (int j = 0; j < 8; ++j) w[j] = *(const float4*)(cw + (c0 + j) * 4);
#pragma unroll
  for (int k = 0; k < 4; ++k) {
    int lt = l - 3 + k;
    if (lt >= 0) {
      bf16x8 v = *(const bf16x8*)(xz + (size_t)lt * 4096 + c0);
      const float* wk = (const float*)w;
#pragma unroll
      for (int j = 0; j < 8; ++j)
        acc[j] = fmaf(bf2f((unsigned short)v[j]), wk[j * 4 + k], acc[j]);
    }
  }
  bf16x8 zr = *(const bf16x8*)(xz + (size_t)l * 4096 + 2048 + c0);
  bf16x8 ox, oz;
#pragma unroll
  for (int j = 0; j < 8; ++j) {
    float a = acc[j];
    ox[j] = (short)f2bf(a / (1.f + __expf(-a)));
    float zv = bf2f((unsigned short)zr[j]);
    oz[j] = (short)f2bf(zv / (1.f + __expf(-zv)));
  }
  *(bf16x8*)(x_ssm + (size_t)idx * 8) = ox;
  *(bf16x8*)(sz_out + (size_t)idx * 8) = oz;
}

// ---------------- chunked parallel scan, thread-per-channel (16 states in regs) ----------
__global__ __launch_bounds__(256) void scan_passA(
    const unsigned short* __restrict__ dtb, const unsigned short* __restrict__ x_ssm,
    const float* __restrict__ x_dbl, const float* __restrict__ A_log,
    float* __restrict__ Pout, float* __restrict__ Hout) {
  int tid = threadIdx.x;
  int c = blockIdx.x & (NCHUNK - 1), db = blockIdx.x >> 7;
  int d = db * 256 + tid;
  int t0 = c * TCHUNK;
  float Av[16];
  const float4* al4 = (const float4*)(A_log + d * 16);
#pragma unroll
  for (int q = 0; q < 4; ++q) {
    float4 a = al4[q];
    Av[q * 4 + 0] = -__expf(a.x); Av[q * 4 + 1] = -__expf(a.y);
    Av[q * 4 + 2] = -__expf(a.z); Av[q * 4 + 3] = -__expf(a.w);
  }
  float h[16];
#pragma unroll
  for (int s = 0; s < 16; ++s) h[s] = 0.f;
  float sum_dt = 0.f;
#pragma unroll 2
  for (int i = 0; i < TCHUNK; ++i) {
    int t = t0 + i;
    float dtv = bf2f(dtb[(size_t)t * 2048 + d]);
    float xv = bf2f(x_ssm[(size_t)t * 2048 + d]);
    float dtx = dtv * xv;
    sum_dt += dtv;
    const float* B = x_dbl + t * 32;  // wave-uniform -> scalar loads
#pragma unroll
    for (int s = 0; s < 16; ++s) {
      float dA = __expf(dtv * Av[s]);
      h[s] = fmaf(dA, h[s], B[s] * dtx);
    }
  }
  float* Ho = Hout + (size_t)c * 32768 + d * 16;
  float* Po = Pout + (size_t)c * 32768 + d * 16;
#pragma unroll
  for (int s = 0; s < 16; ++s) Ho[s] = h[s];
#pragma unroll
  for (int s = 0; s < 16; ++s) Po[s] = __expf(sum_dt * Av[s]);
}

// Pass B: serial combine; rewrites P buffer in-place with chunk-entry states (Hinit).
__global__ __launch_bounds__(256) void scan_passB(
    float* __restrict__ P, const float* __restrict__ Hloc) {
  int i = blockIdx.x * 256 + threadIdx.x;  // 32768 (d,s)
  float h = 0.f;
  for (int c = 0; c < NCHUNK; ++c) {
    size_t o = (size_t)c * 32768 + i;
    float p = P[o];
    float hl = Hloc[o];
    P[o] = h;
    h = fmaf(p, h, hl);
  }
}

// Pass C: re-run chunk from entry state; emit gated y (bf16).
__global__ __launch_bounds__(256) void scan_passC(
    const unsigned short* __restrict__ dtb, const unsigned short* __restrict__ x_ssm,
    const float* __restrict__ x_dbl, const float* __restrict__ A_log,
    const float* __restrict__ D_param, const unsigned short* __restrict__ silu_z,
    const float* __restrict__ Hinit, unsigned short* __restrict__ y_out) {
  int tid = threadIdx.x;
  int c = blockIdx.x & (NCHUNK - 1), db = blockIdx.x >> 7;
  int d = db * 256 + tid;
  int t0 = c * TCHUNK;
  float Av[16];
  const float4* al4 = (const float4*)(A_log + d * 16);
#pragma unroll
  for (int q = 0; q < 4; ++q) {
    float4 a = al4[q];
    Av[q * 4 + 0] = -__expf(a.x); Av[q * 4 + 1] = -__expf(a.y);
    Av[q * 4 + 2] = -__expf(a.z); Av[q * 4 + 3] = -__expf(a.w);
  }
  float Dp = D_param[d];
  float h[16];
  const float4* hi4 = (const float4*)(Hinit + (size_t)c * 32768 + d * 16);
#pragma unroll
  for (int q = 0; q < 4; ++q) {
    float4 v = hi4[q];
    h[q * 4 + 0] = v.x; h[q * 4 + 1] = v.y; h[q * 4 + 2] = v.z; h[q * 4 + 3] = v.w;
  }
#pragma unroll 2
  for (int i = 0; i < TCHUNK; ++i) {
    int t = t0 + i;
    float dtv = bf2f(dtb[(size_t)t * 2048 + d]);
    float xv = bf2f(x_ssm[(size_t)t * 2048 + d]);
    float dtx = dtv * xv;
    const float* B = x_dbl + t * 32;       // uniform
    const float* C = x_dbl + t * 32 + 16;  // uniform
    float y = 0.f;
#pragma unroll
    for (int s = 0; s < 16; ++s) {
      float dA = __expf(dtv * Av[s]);
      h[s] = fmaf(dA, h[s], B[s] * dtx);
      y = fmaf(h[s], C[s], y);
    }
    float szv = bf2f(silu_z[(size_t)t * 2048 + d]);
    y_out[(size_t)t * 2048 + d] = f2bf((y + Dp * xv) * szv);
  }
}

extern "C" void kernel_launch(void* const* d_in, const int* in_sizes, int n_in,
                              void* d_out, int out_size, void* d_ws, size_t ws_size,
                              hipStream_t stream) {
  const float* x      = (const float*)d_in[0];
  const float* W_in   = (const float*)d_in[1];
  const float* conv_w = (const float*)d_in[2];
  const float* conv_b = (const float*)d_in[3];
  const float* A_log  = (const float*)d_in[4];
  const float* D_par  = (const float*)d_in[5];
  const float* W_x    = (const float*)d_in[6];
  const float* W_dt   = (const float*)d_in[7];
  const float* b_dt   = (const float*)d_in[8];
  const float* W_out  = (const float*)d_in[9];
  float* out = (float*)d_out;

  char* ws = (char*)d_ws;
  unsigned short* xbf    = (unsigned short*)(ws + 0);                    // 4MB
  unsigned short* Winbf  = (unsigned short*)(ws + ((size_t)4 << 20));    // 8MB
  unsigned short* Wcomb  = (unsigned short*)(ws + ((size_t)12 << 20));   // 8.5MB [2176][2048]
  unsigned short* Woutbf = (unsigned short*)(ws + ((size_t)21 << 20));   // 4MB
  unsigned short* xz     = (unsigned short*)(ws + ((size_t)25 << 20));   // 16MB (free after conv)
  unsigned short* xssm   = (unsigned short*)(ws + ((size_t)41 << 20));   // 8MB (free after passC)
  unsigned short* siluz  = (unsigned short*)(ws + ((size_t)49 << 20));   // 8MB (free after passC)
  unsigned short* dtb    = (unsigned short*)(ws + ((size_t)57 << 20));   // 8MB (bf16 dt)
  float* xdbl            = (float*)(ws + ((size_t)65 << 20));            // 256KB
  unsigned short* yfin   = (unsigned short*)(ws + ((size_t)66 << 20));   // 8MB
  float* Pbuf            = (float*)(ws + ((size_t)25 << 20));            // 16MB (alias xz)
  float* Hloc            = (float*)(ws + ((size_t)4 << 20));             // 16MB (alias Winbf+Wcomb)
  float* part            = (float*)(ws + ((size_t)41 << 20));            // 16MB (alias xssm+siluz)

  // fp32 -> bf16 converts
  cvt_f32_bf16<<<2048, 256, 0, stream>>>((const float4*)x, (ushort4*)xbf, (L_SEQ * DMODEL) / 4);
  cvt_f32_bf16<<<4096, 256, 0, stream>>>((const float4*)W_in, (ushort4*)Winbf, (2 * DINNER * DMODEL) / 4);
  // Wcomb rows 0..2047 = W_dt, rows 2048..2079 = W_x, rows 2080..2175 = 0
  cvt_f32_bf16<<<4096, 256, 0, stream>>>((const float4*)W_dt, (ushort4*)Wcomb, (DINNER * DINNER) / 4);
  cvt_f32_bf16<<<64, 256, 0, stream>>>((const float4*)W_x, (ushort4*)(Wcomb + (size_t)2048 * 2048),
                                       (32 * DINNER) / 4);
  zero_bf16<<<192, 256, 0, stream>>>((ushort4*)(Wcomb + (size_t)2080 * 2048), (96 * DINNER) / 4);
  cvt_f32_bf16<<<2048, 256, 0, stream>>>((const float4*)W_out, (ushort4*)Woutbf, (DMODEL * DINNER) / 4);

  // GEMM1: xz[2048,4096] = x @ W_in^T  (bf16 out) — 512 blocks
  gemm_bt3<0><<<512, 256, 0, stream>>>(xbf, Winbf, L_SEQ, 4096, DMODEL, 32, 1,
                                       nullptr, xz, nullptr);

  // conv + silu -> x_ssm; silu(z)
  conv_silu8<<<2048, 256, 0, stream>>>(xz, conv_w, conv_b, xssm, siluz);

  // GEMM2 (fused): dt bf16 [2048,2048] (softplus) + x_dbl f32 [2048,32] — 272 blocks
  gemm_bt3<3><<<272, 256, 0, stream>>>(xssm, Wcomb, L_SEQ, 2176, DINNER, 17, 1,
                                       xdbl, dtb, b_dt);

  // chunked parallel scan
  scan_passA<<<NCHUNK * (DINNER / 256), 256, 0, stream>>>(dtb, xssm, xdbl, A_log, Pbuf, Hloc);
  scan_passB<<<(DINNER * 16) / 256, 256, 0, stream>>>(Pbuf, Hloc);
  scan_passC<<<NCHUNK * (DINNER / 256), 256, 0, stream>>>(dtb, xssm, xdbl, A_log, D_par, siluz,
                                                          Pbuf, yfin);

  // GEMM4: split-K x2 partials [2,2048,1024] f32 — 256 blocks
  gemm_bt3<4><<<256, 256, 0, stream>>>(yfin, Woutbf, L_SEQ, DMODEL, DINNER, 8, 2,
                                       part, nullptr, nullptr);
  // out = p0 + p1 + x
  reduce_addx<<<(L_SEQ * DMODEL / 4 + 255) / 256, 256, 0, stream>>>(
      (const float4*)part, (const float4*)x, (float4*)out, L_SEQ * DMODEL / 4);
}